// Round 8
// baseline (282.110 us; speedup 1.0000x reference)
//
#include <hip/hip_runtime.h>
#include <hip/hip_fp16.h>

// ---- shape constants (N=100000 <= 131072 so src fits in 17 bits) ----
#define SB_SHIFT 9
#define SB_SIZE 512             // nodes per super-bucket
#define MAXSB 256               // padded super-bucket array size (nsb=196)
#define BIN_CHUNK 16384         // edges per binA block (runs of ~84 edges/bucket)
#define SRC_BITS 17
#define SRC_MASK 0x1FFFF
#define NODES_PER_BLOCK 64      // mm1 tile

__global__ void zero_i_kernel(int* __restrict__ p, int total) {
  int i = blockIdx.x * blockDim.x + threadIdx.x;
  if (i < total) p[i] = 0;
}

// super-bucket histogram of col>>9 (LDS-privatized, int atomics)
__global__ __launch_bounds__(512) void histA_kernel(const int* __restrict__ col,
                                                    int* __restrict__ bcnt, int e, int nsb) {
  __shared__ int lc[MAXSB];
  int t = threadIdx.x;
  for (int i = t; i < MAXSB; i += 512) lc[i] = 0;
  __syncthreads();
  for (int i = blockIdx.x * 512 + t; i < e; i += gridDim.x * 512)
    atomicAdd(&lc[col[i] >> SB_SHIFT], 1);
  __syncthreads();
  for (int i = t; i < nsb; i += 512)
    if (lc[i]) atomicAdd(&bcnt[i], lc[i]);
}

// exclusive scan over nsb (<=256) counts -> sbstart[0..nsb], bcur copy
__global__ __launch_bounds__(512) void scanA_kernel(const int* __restrict__ bcnt,
                                                    int* __restrict__ sbstart,
                                                    int* __restrict__ bcur, int nsb) {
  __shared__ int lds[512];
  int t = threadIdx.x;
  int v = (t < nsb) ? bcnt[t] : 0;
  lds[t] = v;
  __syncthreads();
  for (int off = 1; off < 512; off <<= 1) {
    int u = (t >= off) ? lds[t - off] : 0;
    __syncthreads();
    lds[t] += u;
    __syncthreads();
  }
  int excl = lds[t] - v;
  if (t < nsb) { sbstart[t] = excl; bcur[t] = excl; }
  if (t == 511) sbstart[nsb] = lds[511];
}

// pass A: scatter into super-bucket groups; pairsA = src | colLow9<<17
__global__ __launch_bounds__(512) void binA_kernel(const int* __restrict__ row,
                                                   const int* __restrict__ col,
                                                   int* __restrict__ bcur,
                                                   int* __restrict__ pairsA, int e) {
  __shared__ int lc[MAXSB];
  __shared__ int lcur[MAXSB];
  int t = threadIdx.x;
  int i0 = blockIdx.x * BIN_CHUNK;
  int i1 = min(i0 + BIN_CHUNK, e);
  for (int i = t; i < MAXSB; i += 512) lc[i] = 0;
  __syncthreads();
  for (int i = i0 + t; i < i1; i += 512) atomicAdd(&lc[col[i] >> SB_SHIFT], 1);
  __syncthreads();
  for (int i = t; i < MAXSB; i += 512)
    lcur[i] = lc[i] ? atomicAdd(&bcur[i], lc[i]) : 0;
  __syncthreads();
  for (int i = i0 + t; i < i1; i += 512) {
    int c = col[i];
    int b = c >> SB_SHIFT;
    int pos = atomicAdd(&lcur[b], 1);
    pairsA[pos] = row[i] | ((c & (SB_SIZE - 1)) << SRC_BITS);
  }
}

// pass B: per super-bucket counting sort by local col -> node-sorted src array,
// node_start[] and dinv[] fall out of the histogram for free
__global__ __launch_bounds__(512) void sortB_kernel(const int* __restrict__ pairsA,
                                                    const int* __restrict__ sbstart,
                                                    int* __restrict__ pairs,
                                                    int* __restrict__ node_start,
                                                    float* __restrict__ dinv, int n) {
  __shared__ int cnt[SB_SIZE];
  __shared__ int base[SB_SIZE];
  __shared__ int cur[SB_SIZE];
  int b = blockIdx.x, t = threadIdx.x;
  int e0 = sbstart[b], e1 = sbstart[b + 1];
  if (t < SB_SIZE) cnt[t] = 0;
  __syncthreads();
  for (int i = e0 + t; i < e1; i += 512) atomicAdd(&cnt[pairsA[i] >> SRC_BITS], 1);
  __syncthreads();
  if (t < SB_SIZE) base[t] = cnt[t];
  __syncthreads();
  for (int off = 1; off < SB_SIZE; off <<= 1) {
    int u = (t < SB_SIZE && t >= off) ? base[t - off] : 0;
    __syncthreads();
    if (t < SB_SIZE) base[t] += u;
    __syncthreads();
  }
  if (t < SB_SIZE) {
    int excl = base[t] - cnt[t];
    base[t] = excl;
    cur[t] = excl;
    int node = (b << SB_SHIFT) + t;
    node_start[node] = e0 + excl;
    dinv[node] = rsqrtf((float)cnt[t] + 1.0f);
  }
  __syncthreads();
  for (int i = e0 + t; i < e1; i += 512) {
    int v = pairsA[i];
    int pos = e0 + atomicAdd(&cur[v >> SRC_BITS], 1);
    pairs[pos] = v & SRC_MASK;
  }
}

// s1 = fp16( (x @ W1) * dinv ) ; 32 B/row -> L2-resident table
__global__ __launch_bounds__(256) void mm1_kernel(const float* __restrict__ x,
                                                  const float* __restrict__ W1,
                                                  const float* __restrict__ dinv,
                                                  __half* __restrict__ s1, int n) {
  __shared__ float xs[NODES_PER_BLOCK][129];
  __shared__ float ws[128 * 16];
  int t = threadIdx.x;
  for (int i = t; i < 128 * 16; i += 256) ws[i] = W1[i];
  int base = blockIdx.x * NODES_PER_BLOCK;
  for (int i = t * 4; i < NODES_PER_BLOCK * 128; i += 256 * 4) {
    int nn = i >> 7, k = i & 127;
    if (base + nn < n) {
      float4 v = *(const float4*)(x + (size_t)(base + nn) * 128 + k);
      xs[nn][k] = v.x; xs[nn][k + 1] = v.y; xs[nn][k + 2] = v.z; xs[nn][k + 3] = v.w;
    }
  }
  __syncthreads();
  int nn = t >> 2;
  int j0 = (t & 3) * 4;
  float a0 = 0, a1 = 0, a2 = 0, a3 = 0;
  #pragma unroll 8
  for (int k = 0; k < 128; k++) {
    float xv = xs[nn][k];
    const float* wr = ws + k * 16 + j0;
    a0 += xv * wr[0]; a1 += xv * wr[1]; a2 += xv * wr[2]; a3 += xv * wr[3];
  }
  int node = base + nn;
  if (node < n) {
    float d = dinv[node];
    __half2 p0 = __floats2half2_rn(a0 * d, a1 * d);
    __half2 p1 = __floats2half2_rn(a2 * d, a3 * d);
    union { struct { __half2 a, b; } h; uint2 u; } pk;
    pk.h.a = p0; pk.h.b = p1;
    *(uint2*)(s1 + (size_t)node * 16 + j0) = pk.u;
  }
}

union H4 { float2 f2; __half2 h2[2]; };

// layer-1: contiguous-run register aggregation + fused relu/bias/rescale
__global__ __launch_bounds__(512) void agg1_kernel(const int* __restrict__ pairs,
                                                   const int* __restrict__ node_start,
                                                   const __half* __restrict__ s1,
                                                   const float* __restrict__ dinv,
                                                   const float* __restrict__ b1,
                                                   __half* __restrict__ s2, int n) {
  __shared__ float lb1[16];
  int t = threadIdx.x;
  if (t < 16) lb1[t] = b1[t];
  __syncthreads();
  int node = blockIdx.x * 128 + (t >> 2);
  int q = t & 3;             // feature quad (4 halfs = 8 B)
  if (node >= n) return;     // no barriers after this point
  H4 u; u.f2 = *(const float2*)(s1 + (size_t)node * 16 + 4 * q);  // self loop
  float2 lo = __half22float2(u.h2[0]), hi = __half22float2(u.h2[1]);
  float a0 = lo.x, a1 = lo.y, a2 = hi.x, a3 = hi.y;
  int j = node_start[node], en = node_start[node + 1];
  for (; j + 3 < en; j += 4) {
    int s0 = pairs[j], s1i = pairs[j + 1], s2i = pairs[j + 2], s3i = pairs[j + 3];
    H4 w0, w1, w2, w3;
    w0.f2 = *(const float2*)(s1 + (size_t)s0 * 16 + 4 * q);
    w1.f2 = *(const float2*)(s1 + (size_t)s1i * 16 + 4 * q);
    w2.f2 = *(const float2*)(s1 + (size_t)s2i * 16 + 4 * q);
    w3.f2 = *(const float2*)(s1 + (size_t)s3i * 16 + 4 * q);
    float2 l0 = __half22float2(w0.h2[0]), h0 = __half22float2(w0.h2[1]);
    float2 l1 = __half22float2(w1.h2[0]), h1 = __half22float2(w1.h2[1]);
    float2 l2 = __half22float2(w2.h2[0]), h2 = __half22float2(w2.h2[1]);
    float2 l3 = __half22float2(w3.h2[0]), h3 = __half22float2(w3.h2[1]);
    a0 += l0.x + l1.x + l2.x + l3.x;
    a1 += l0.y + l1.y + l2.y + l3.y;
    a2 += h0.x + h1.x + h2.x + h3.x;
    a3 += h0.y + h1.y + h2.y + h3.y;
  }
  for (; j < en; j++) {
    H4 w; w.f2 = *(const float2*)(s1 + (size_t)pairs[j] * 16 + 4 * q);
    float2 l = __half22float2(w.h2[0]), h = __half22float2(w.h2[1]);
    a0 += l.x; a1 += l.y; a2 += h.x; a3 += h.y;
  }
  float d = dinv[node];
  int f = 4 * q;
  a0 = fmaxf(fmaf(d, a0, lb1[f + 0]), 0.f) * d;
  a1 = fmaxf(fmaf(d, a1, lb1[f + 1]), 0.f) * d;
  a2 = fmaxf(fmaf(d, a2, lb1[f + 2]), 0.f) * d;
  a3 = fmaxf(fmaf(d, a3, lb1[f + 3]), 0.f) * d;
  H4 o; o.h2[0] = __floats2half2_rn(a0, a1); o.h2[1] = __floats2half2_rn(a2, a3);
  *(float2*)(s2 + (size_t)node * 16 + 4 * q) = o.f2;
}

// layer-2: contiguous-run aggregation + fused 16->64 transform -> out (fp32)
__global__ __launch_bounds__(512) void agg2_kernel(const int* __restrict__ pairs,
                                                   const int* __restrict__ node_start,
                                                   const __half* __restrict__ s2,
                                                   const float* __restrict__ dinv,
                                                   const float* __restrict__ W2,
                                                   const float* __restrict__ b2,
                                                   float* __restrict__ out, int n) {
  __shared__ float tile[128 * 16];   // pre-activation (exact ownership, no atomics)
  __shared__ float w2s[16 * 64];
  __shared__ float b2s[64];
  int t = threadIdx.x;
  for (int i = t; i < 16 * 64; i += 512) w2s[i] = W2[i];
  if (t < 64) b2s[t] = b2[t];
  int node_l = t >> 2;
  int q = t & 3;
  int node = blockIdx.x * 128 + node_l;
  if (node < n) {
    H4 u; u.f2 = *(const float2*)(s2 + (size_t)node * 16 + 4 * q);  // self loop
    float2 lo = __half22float2(u.h2[0]), hi = __half22float2(u.h2[1]);
    float a0 = lo.x, a1 = lo.y, a2 = hi.x, a3 = hi.y;
    int j = node_start[node], en = node_start[node + 1];
    for (; j + 3 < en; j += 4) {
      int s0 = pairs[j], s1i = pairs[j + 1], s2i = pairs[j + 2], s3i = pairs[j + 3];
      H4 w0, w1, w2, w3;
      w0.f2 = *(const float2*)(s2 + (size_t)s0 * 16 + 4 * q);
      w1.f2 = *(const float2*)(s2 + (size_t)s1i * 16 + 4 * q);
      w2.f2 = *(const float2*)(s2 + (size_t)s2i * 16 + 4 * q);
      w3.f2 = *(const float2*)(s2 + (size_t)s3i * 16 + 4 * q);
      float2 l0 = __half22float2(w0.h2[0]), h0 = __half22float2(w0.h2[1]);
      float2 l1 = __half22float2(w1.h2[0]), h1 = __half22float2(w1.h2[1]);
      float2 l2 = __half22float2(w2.h2[0]), h2 = __half22float2(w2.h2[1]);
      float2 l3 = __half22float2(w3.h2[0]), h3 = __half22float2(w3.h2[1]);
      a0 += l0.x + l1.x + l2.x + l3.x;
      a1 += l0.y + l1.y + l2.y + l3.y;
      a2 += h0.x + h1.x + h2.x + h3.x;
      a3 += h0.y + h1.y + h2.y + h3.y;
    }
    for (; j < en; j++) {
      H4 w; w.f2 = *(const float2*)(s2 + (size_t)pairs[j] * 16 + 4 * q);
      float2 l = __half22float2(w.h2[0]), h = __half22float2(w.h2[1]);
      a0 += l.x; a1 += l.y; a2 += h.x; a3 += h.y;
    }
    float d = dinv[node];
    float* tp = tile + node_l * 16 + 4 * q;
    tp[0] = a0 * d; tp[1] = a1 * d; tp[2] = a2 * d; tp[3] = a3 * d;
  }
  __syncthreads();
  int base = blockIdx.x * 128;
  for (int idx = t; idx < 128 * 64; idx += 512) {
    int r = idx >> 6, jj = idx & 63;
    int onode = base + r;
    if (onode < n) {
      float o = b2s[jj];
      #pragma unroll
      for (int k = 0; k < 16; k++) o = fmaf(tile[r * 16 + k], w2s[k * 64 + jj], o);
      out[(size_t)onode * 64 + jj] = o;
    }
  }
}

extern "C" void kernel_launch(void* const* d_in, const int* in_sizes, int n_in,
                              void* d_out, int out_size, void* d_ws, size_t ws_size,
                              hipStream_t stream) {
  const float* x = (const float*)d_in[0];
  const int* ei = (const int*)d_in[1];   // int32 (JAX x64 disabled)
  const float* W1 = (const float*)d_in[2];
  const float* b1 = (const float*)d_in[3];
  const float* W2 = (const float*)d_in[4];
  const float* b2 = (const float*)d_in[5];
  float* out = (float*)d_out;

  int n = in_sizes[0] / 128;   // 100000
  int e = in_sizes[1] / 2;     // 3200000
  const int* row = ei;         // sources
  const int* col = ei + e;     // targets (aggregation index)
  int nsb = (n + SB_SIZE - 1) >> SB_SHIFT;   // 196 super-buckets

  // workspace layout (ints; regions 16B-aligned). s1/s2 overlap dead pairsA.
  int* bcnt = (int*)d_ws;                     // 256
  int* sbstart = bcnt + 256;                  // 256+16
  int* bcur = sbstart + 272;                  // 256
  int* pairsA = bcur + 256;                   // e  (12.8 MB; dead after sortB)
  int* pairs = pairsA + e;                    // e  (12.8 MB)
  int* node_start = pairs + e;                // nsb*512+16
  float* dinv = (float*)(node_start + MAXSB * SB_SIZE + 16);  // nsb*512
  __half* s1 = (__half*)pairsA;               // 16n halfs = 3.2 MB (inside pairsA)
  __half* s2 = s1 + (size_t)n * 16;           // 16n halfs = 3.2 MB (inside pairsA)

  // ---- node-sorted edge build (once; shared by both layers) ----
  zero_i_kernel<<<1, 256, 0, stream>>>(bcnt, 256);
  histA_kernel<<<256, 512, 0, stream>>>(col, bcnt, e, nsb);
  scanA_kernel<<<1, 512, 0, stream>>>(bcnt, sbstart, bcur, nsb);
  binA_kernel<<<(e + BIN_CHUNK - 1) / BIN_CHUNK, 512, 0, stream>>>(row, col, bcur, pairsA, e);
  sortB_kernel<<<nsb, 512, 0, stream>>>(pairsA, sbstart, pairs, node_start, dinv, n);

  // ---- layer 1: transform (128->16) -> fp16 table, run-gather aggregate ----
  mm1_kernel<<<(n + NODES_PER_BLOCK - 1) / NODES_PER_BLOCK, 256, 0, stream>>>(x, W1, dinv, s1, n);
  agg1_kernel<<<(n + 127) / 128, 512, 0, stream>>>(pairs, node_start, s1, dinv, b1, s2, n);

  // ---- layer 2: run-gather aggregate + fused 16->64 transform ----
  agg2_kernel<<<(n + 127) / 128, 512, 0, stream>>>(pairs, node_start, s2, dinv, W2, b2, out, n);
}

// Round 9
// 263.456 us; speedup vs baseline: 1.0708x; 1.0708x over previous
//
#include <hip/hip_runtime.h>
#include <hip/hip_fp16.h>

// ---- shape constants (N=100000 <= 131072 so src fits in 17 bits) ----
#define SB_SHIFT 8
#define SB_SIZE 256             // nodes per super-bucket (sortB parallelism: nsb=391)
#define MAXSB 512               // padded super-bucket array size
#define BIN_CHUNK 16384         // edges per binA chunk (runs of ~42 edges)
#define SRC_BITS 17
#define SRC_MASK 0x1FFFF
#define NODES_PER_BLOCK 64      // mm1 tile

__global__ void zero_i_kernel(int* __restrict__ p, int total) {
  int i = blockIdx.x * blockDim.x + threadIdx.x;
  if (i < total) p[i] = 0;
}

// per-chunk histogram of col>>8 -> cntM[chunk][*], plus global totals bcnt
__global__ __launch_bounds__(512) void histA_kernel(const int* __restrict__ col,
                                                    int* __restrict__ bcnt,
                                                    int* __restrict__ cntM,
                                                    int e, int nsb) {
  __shared__ int lc[MAXSB];
  int t = threadIdx.x;
  int chunk = blockIdx.x;
  int i0 = chunk * BIN_CHUNK;
  int i1 = min(i0 + BIN_CHUNK, e);
  for (int i = t; i < MAXSB; i += 512) lc[i] = 0;
  __syncthreads();
  for (int i = i0 + t; i < i1; i += 512)
    atomicAdd(&lc[col[i] >> SB_SHIFT], 1);
  __syncthreads();
  int* cm = cntM + (size_t)chunk * MAXSB;
  for (int i = t; i < MAXSB; i += 512) {
    int v = lc[i];
    cm[i] = v;
    if (i < nsb && v) atomicAdd(&bcnt[i], v);
  }
}

// exclusive scan over nsb (<=512) counts -> sbstart[0..nsb], bcur copy
__global__ __launch_bounds__(512) void scanA_kernel(const int* __restrict__ bcnt,
                                                    int* __restrict__ sbstart,
                                                    int* __restrict__ bcur, int nsb) {
  __shared__ int lds[512];
  int t = threadIdx.x;
  int v = (t < nsb) ? bcnt[t] : 0;
  lds[t] = v;
  __syncthreads();
  for (int off = 1; off < 512; off <<= 1) {
    int u = (t >= off) ? lds[t - off] : 0;
    __syncthreads();
    lds[t] += u;
    __syncthreads();
  }
  int excl = lds[t] - v;
  if (t < nsb) { sbstart[t] = excl; bcur[t] = excl; }
  if (t == 511) sbstart[nsb] = lds[511];
}

// pass A: scatter into super-bucket groups; pairsA = src | colLow8<<17
// chunk counts come precomputed from cntM (no re-histogram)
__global__ __launch_bounds__(512) void binA_kernel(const int* __restrict__ row,
                                                   const int* __restrict__ col,
                                                   const int* __restrict__ cntM,
                                                   int* __restrict__ bcur,
                                                   int* __restrict__ pairsA, int e) {
  __shared__ int lcur[MAXSB];
  int t = threadIdx.x;
  int chunk = blockIdx.x;
  int i0 = chunk * BIN_CHUNK;
  int i1 = min(i0 + BIN_CHUNK, e);
  const int* cm = cntM + (size_t)chunk * MAXSB;
  for (int i = t; i < MAXSB; i += 512) {
    int c = cm[i];
    lcur[i] = c ? atomicAdd(&bcur[i], c) : 0;
  }
  __syncthreads();
  for (int i = i0 + t; i < i1; i += 512) {
    int c = col[i];
    int b = c >> SB_SHIFT;
    int pos = atomicAdd(&lcur[b], 1);
    pairsA[pos] = row[i] | ((c & (SB_SIZE - 1)) << SRC_BITS);
  }
}

// pass B: per super-bucket counting sort by local col -> node-sorted src array,
// node_start[] and dinv[] fall out of the histogram for free
__global__ __launch_bounds__(512) void sortB_kernel(const int* __restrict__ pairsA,
                                                    const int* __restrict__ sbstart,
                                                    int* __restrict__ pairs,
                                                    int* __restrict__ node_start,
                                                    float* __restrict__ dinv, int n) {
  __shared__ int cnt[SB_SIZE];
  __shared__ int base[SB_SIZE];
  __shared__ int cur[SB_SIZE];
  int b = blockIdx.x, t = threadIdx.x;
  int e0 = sbstart[b], e1 = sbstart[b + 1];
  if (t < SB_SIZE) cnt[t] = 0;
  __syncthreads();
  for (int i = e0 + t; i < e1; i += 512) atomicAdd(&cnt[pairsA[i] >> SRC_BITS], 1);
  __syncthreads();
  if (t < SB_SIZE) base[t] = cnt[t];
  __syncthreads();
  for (int off = 1; off < SB_SIZE; off <<= 1) {
    int u = (t < SB_SIZE && t >= off) ? base[t - off] : 0;
    __syncthreads();
    if (t < SB_SIZE) base[t] += u;
    __syncthreads();
  }
  if (t < SB_SIZE) {
    int excl = base[t] - cnt[t];
    cur[t] = excl;
    int node = (b << SB_SHIFT) + t;
    node_start[node] = e0 + excl;
    dinv[node] = rsqrtf((float)cnt[t] + 1.0f);
  }
  __syncthreads();
  for (int i = e0 + t; i < e1; i += 512) {
    int v = pairsA[i];
    int pos = e0 + atomicAdd(&cur[v >> SRC_BITS], 1);
    pairs[pos] = v & SRC_MASK;
  }
}

// s1 = fp16( (x @ W1) * dinv ) ; 32 B/row -> L2-resident table
__global__ __launch_bounds__(256) void mm1_kernel(const float* __restrict__ x,
                                                  const float* __restrict__ W1,
                                                  const float* __restrict__ dinv,
                                                  __half* __restrict__ s1, int n) {
  __shared__ float xs[NODES_PER_BLOCK][129];
  __shared__ float ws[128 * 16];
  int t = threadIdx.x;
  for (int i = t; i < 128 * 16; i += 256) ws[i] = W1[i];
  int base = blockIdx.x * NODES_PER_BLOCK;
  for (int i = t * 4; i < NODES_PER_BLOCK * 128; i += 256 * 4) {
    int nn = i >> 7, k = i & 127;
    if (base + nn < n) {
      float4 v = *(const float4*)(x + (size_t)(base + nn) * 128 + k);
      xs[nn][k] = v.x; xs[nn][k + 1] = v.y; xs[nn][k + 2] = v.z; xs[nn][k + 3] = v.w;
    }
  }
  __syncthreads();
  int nn = t >> 2;
  int j0 = (t & 3) * 4;
  float a0 = 0, a1 = 0, a2 = 0, a3 = 0;
  #pragma unroll 8
  for (int k = 0; k < 128; k++) {
    float xv = xs[nn][k];
    const float* wr = ws + k * 16 + j0;
    a0 += xv * wr[0]; a1 += xv * wr[1]; a2 += xv * wr[2]; a3 += xv * wr[3];
  }
  int node = base + nn;
  if (node < n) {
    float d = dinv[node];
    __half2 p0 = __floats2half2_rn(a0 * d, a1 * d);
    __half2 p1 = __floats2half2_rn(a2 * d, a3 * d);
    union { struct { __half2 a, b; } h; uint2 u; } pk;
    pk.h.a = p0; pk.h.b = p1;
    *(uint2*)(s1 + (size_t)node * 16 + j0) = pk.u;
  }
}

union H4 { float2 f2; __half2 h2[2]; };

__device__ __forceinline__ void acc_h4(const __half* __restrict__ tbl, int src, int q,
                                       float& a0, float& a1, float& a2, float& a3) {
  H4 w; w.f2 = *(const float2*)(tbl + (size_t)src * 16 + 4 * q);
  float2 l = __half22float2(w.h2[0]), h = __half22float2(w.h2[1]);
  a0 += l.x; a1 += l.y; a2 += h.x; a3 += h.y;
}

// layer-1: contiguous-run register aggregation + fused relu/bias/rescale
__global__ __launch_bounds__(512) void agg1_kernel(const int* __restrict__ pairs,
                                                   const int* __restrict__ node_start,
                                                   const __half* __restrict__ s1,
                                                   const float* __restrict__ dinv,
                                                   const float* __restrict__ b1,
                                                   __half* __restrict__ s2, int n) {
  __shared__ float lb1[16];
  int t = threadIdx.x;
  if (t < 16) lb1[t] = b1[t];
  __syncthreads();
  int node = blockIdx.x * 128 + (t >> 2);
  int q = t & 3;             // feature quad (4 halfs = 8 B)
  if (node >= n) return;     // no barriers after this point
  H4 u; u.f2 = *(const float2*)(s1 + (size_t)node * 16 + 4 * q);  // self loop
  float2 lo = __half22float2(u.h2[0]), hi = __half22float2(u.h2[1]);
  float a0 = lo.x, a1 = lo.y, a2 = hi.x, a3 = hi.y;
  int j = node_start[node], en = node_start[node + 1];
  for (; j + 7 < en; j += 8) {
    int p0 = pairs[j],     p1 = pairs[j + 1], p2 = pairs[j + 2], p3 = pairs[j + 3];
    int p4 = pairs[j + 4], p5 = pairs[j + 5], p6 = pairs[j + 6], p7 = pairs[j + 7];
    acc_h4(s1, p0, q, a0, a1, a2, a3); acc_h4(s1, p1, q, a0, a1, a2, a3);
    acc_h4(s1, p2, q, a0, a1, a2, a3); acc_h4(s1, p3, q, a0, a1, a2, a3);
    acc_h4(s1, p4, q, a0, a1, a2, a3); acc_h4(s1, p5, q, a0, a1, a2, a3);
    acc_h4(s1, p6, q, a0, a1, a2, a3); acc_h4(s1, p7, q, a0, a1, a2, a3);
  }
  for (; j < en; j++) acc_h4(s1, pairs[j], q, a0, a1, a2, a3);
  float d = dinv[node];
  int f = 4 * q;
  a0 = fmaxf(fmaf(d, a0, lb1[f + 0]), 0.f) * d;
  a1 = fmaxf(fmaf(d, a1, lb1[f + 1]), 0.f) * d;
  a2 = fmaxf(fmaf(d, a2, lb1[f + 2]), 0.f) * d;
  a3 = fmaxf(fmaf(d, a3, lb1[f + 3]), 0.f) * d;
  H4 o; o.h2[0] = __floats2half2_rn(a0, a1); o.h2[1] = __floats2half2_rn(a2, a3);
  *(float2*)(s2 + (size_t)node * 16 + 4 * q) = o.f2;
}

// layer-2: contiguous-run aggregation + fused 16->64 transform -> out (fp32)
__global__ __launch_bounds__(512) void agg2_kernel(const int* __restrict__ pairs,
                                                   const int* __restrict__ node_start,
                                                   const __half* __restrict__ s2,
                                                   const float* __restrict__ dinv,
                                                   const float* __restrict__ W2,
                                                   const float* __restrict__ b2,
                                                   float* __restrict__ out, int n) {
  __shared__ float tile[128 * 16];   // pre-activation (exact ownership, no atomics)
  __shared__ float w2s[16 * 64];
  __shared__ float b2s[64];
  int t = threadIdx.x;
  for (int i = t; i < 16 * 64; i += 512) w2s[i] = W2[i];
  if (t < 64) b2s[t] = b2[t];
  int node_l = t >> 2;
  int q = t & 3;
  int node = blockIdx.x * 128 + node_l;
  if (node < n) {
    H4 u; u.f2 = *(const float2*)(s2 + (size_t)node * 16 + 4 * q);  // self loop
    float2 lo = __half22float2(u.h2[0]), hi = __half22float2(u.h2[1]);
    float a0 = lo.x, a1 = lo.y, a2 = hi.x, a3 = hi.y;
    int j = node_start[node], en = node_start[node + 1];
    for (; j + 7 < en; j += 8) {
      int p0 = pairs[j],     p1 = pairs[j + 1], p2 = pairs[j + 2], p3 = pairs[j + 3];
      int p4 = pairs[j + 4], p5 = pairs[j + 5], p6 = pairs[j + 6], p7 = pairs[j + 7];
      acc_h4(s2, p0, q, a0, a1, a2, a3); acc_h4(s2, p1, q, a0, a1, a2, a3);
      acc_h4(s2, p2, q, a0, a1, a2, a3); acc_h4(s2, p3, q, a0, a1, a2, a3);
      acc_h4(s2, p4, q, a0, a1, a2, a3); acc_h4(s2, p5, q, a0, a1, a2, a3);
      acc_h4(s2, p6, q, a0, a1, a2, a3); acc_h4(s2, p7, q, a0, a1, a2, a3);
    }
    for (; j < en; j++) acc_h4(s2, pairs[j], q, a0, a1, a2, a3);
    float d = dinv[node];
    float* tp = tile + node_l * 16 + 4 * q;
    tp[0] = a0 * d; tp[1] = a1 * d; tp[2] = a2 * d; tp[3] = a3 * d;
  }
  __syncthreads();
  int base = blockIdx.x * 128;
  for (int idx = t; idx < 128 * 64; idx += 512) {
    int r = idx >> 6, jj = idx & 63;
    int onode = base + r;
    if (onode < n) {
      float o = b2s[jj];
      #pragma unroll
      for (int k = 0; k < 16; k++) o = fmaf(tile[r * 16 + k], w2s[k * 64 + jj], o);
      out[(size_t)onode * 64 + jj] = o;
    }
  }
}

extern "C" void kernel_launch(void* const* d_in, const int* in_sizes, int n_in,
                              void* d_out, int out_size, void* d_ws, size_t ws_size,
                              hipStream_t stream) {
  const float* x = (const float*)d_in[0];
  const int* ei = (const int*)d_in[1];   // int32 (JAX x64 disabled)
  const float* W1 = (const float*)d_in[2];
  const float* b1 = (const float*)d_in[3];
  const float* W2 = (const float*)d_in[4];
  const float* b2 = (const float*)d_in[5];
  float* out = (float*)d_out;

  int n = in_sizes[0] / 128;   // 100000
  int e = in_sizes[1] / 2;     // 3200000
  const int* row = ei;         // sources
  const int* col = ei + e;     // targets (aggregation index)
  int nsb = (n + SB_SIZE - 1) >> SB_SHIFT;           // 391 super-buckets
  int nchunks = (e + BIN_CHUNK - 1) / BIN_CHUNK;     // 196 chunks

  // workspace layout (ints; regions 16B-aligned). s1/s2 overlap dead pairsA.
  int* bcnt = (int*)d_ws;                     // 512
  int* sbstart = bcnt + 512;                  // 512+16
  int* bcur = sbstart + 528;                  // 512
  int* cntM = bcur + 512;                     // nchunks*MAXSB (<= 256*512)
  int* pairsA = cntM + 256 * MAXSB;           // e  (12.8 MB; dead after sortB)
  int* pairs = pairsA + e;                    // e  (12.8 MB)
  int* node_start = pairs + e;                // 512*256+16
  float* dinv = (float*)(node_start + 512 * 256 + 16);  // 512*256
  __half* s1 = (__half*)pairsA;               // 16n halfs = 3.2 MB (inside pairsA)
  __half* s2 = s1 + (size_t)n * 16;           // 16n halfs = 3.2 MB (inside pairsA)

  // ---- node-sorted edge build (once; shared by both layers) ----
  zero_i_kernel<<<1, 512, 0, stream>>>(bcnt, 512);
  histA_kernel<<<nchunks, 512, 0, stream>>>(col, bcnt, cntM, e, nsb);
  scanA_kernel<<<1, 512, 0, stream>>>(bcnt, sbstart, bcur, nsb);
  binA_kernel<<<nchunks, 512, 0, stream>>>(row, col, cntM, bcur, pairsA, e);
  sortB_kernel<<<nsb, 512, 0, stream>>>(pairsA, sbstart, pairs, node_start, dinv, n);

  // ---- layer 1: transform (128->16) -> fp16 table, run-gather aggregate ----
  mm1_kernel<<<(n + NODES_PER_BLOCK - 1) / NODES_PER_BLOCK, 256, 0, stream>>>(x, W1, dinv, s1, n);
  agg1_kernel<<<(n + 127) / 128, 512, 0, stream>>>(pairs, node_start, s1, dinv, b1, s2, n);

  // ---- layer 2: run-gather aggregate + fused 16->64 transform ----
  agg2_kernel<<<(n + 127) / 128, 512, 0, stream>>>(pairs, node_start, s2, dinv, W2, b2, out, n);
}